// Round 2
// baseline (1555.685 us; speedup 1.0000x reference)
//
#include <hip/hip_runtime.h>

// HeteroGAT: 2-layer bipartite GAT (heads=4,ch=25 concat + edge feat; then heads=1,ch=100).
// R2: parallel 3-kernel CSR scan (old 2-block scan was 113us @ 0.27% occupancy),
//     fused gemm/gather launches (grid.y = which), 2-edge unrolled gathers.

#define NNODES 50000
#define NEDGES 800000
#define SCAN_T 1024
#define SCAN_NBLK ((NNODES + SCAN_T - 1) / SCAN_T)  // 49

// ---------------- ce[h] = sum_c We[h*25+c]*ae[h*25+c] (edge-attn constant) ----------------
__global__ void ce_kernel(const float* __restrict__ WeA, const float* __restrict__ aeA,
                          const float* __restrict__ WeB, const float* __restrict__ aeB,
                          float* __restrict__ ce /*[8]: 0..3=AB, 4..7=BA*/) {
    const float* We = blockIdx.x ? WeB : WeA;
    const float* ae = blockIdx.x ? aeB : aeA;
    __shared__ float s[4];
    int tid = threadIdx.x;
    if (tid < 4) s[tid] = 0.f;
    __syncthreads();
    if (tid < 100) atomicAdd(&s[tid / 25], We[tid] * ae[tid]);
    __syncthreads();
    if (tid < 4) ce[blockIdx.x * 4 + tid] = s[tid];
}

// ---------------- CSR build ----------------
__global__ void count_kernel(const int* __restrict__ eiA, const int* __restrict__ eiB,
                             int E, int* cntA, int* cntB) {
    int i = blockIdx.x * blockDim.x + threadIdx.x;
    if (i < E) atomicAdd(&cntA[eiA[E + i]], 1);
    else if (i < 2 * E) atomicAdd(&cntB[eiB[E + (i - E)]], 1);
}

// inclusive block-scan of cnt into ro[i+1] (no cross-block offset yet) + block totals
__global__ __launch_bounds__(SCAN_T) void scanA_kernel(
    const int* __restrict__ cntA, const int* __restrict__ cntB,
    int* __restrict__ roA, int* __restrict__ roB, int* __restrict__ partial, int N) {
    const int dir = blockIdx.y;
    const int* cnt = dir ? cntB : cntA;
    int* ro = dir ? roB : roA;
    const int tid = threadIdx.x;
    const int i = blockIdx.x * SCAN_T + tid;
    __shared__ int sm[SCAN_T];
    sm[tid] = (i < N) ? cnt[i] : 0;
    __syncthreads();
    for (int off = 1; off < SCAN_T; off <<= 1) {
        int t = (tid >= off) ? sm[tid - off] : 0;
        __syncthreads();
        sm[tid] += t;
        __syncthreads();
    }
    if (i < N) ro[i + 1] = sm[tid];
    if (tid == SCAN_T - 1) partial[dir * 64 + blockIdx.x] = sm[tid];
}

// exclusive scan of per-block totals (49 per direction) — tiny, one block
__global__ void scanB_kernel(int* __restrict__ partial, int nblk) {
    __shared__ int sm[128];
    const int tid = threadIdx.x;
    sm[tid] = ((tid & 63) < nblk) ? partial[tid] : 0;
    __syncthreads();
    if (tid < 2) {
        int run = 0;
        for (int b = 0; b < nblk; ++b) {
            int t = sm[tid * 64 + b];
            sm[tid * 64 + b] = run;
            run += t;
        }
    }
    __syncthreads();
    partial[tid] = sm[tid];
}

// add block offsets; derive cur[i] = row start
__global__ __launch_bounds__(SCAN_T) void scanC_kernel(
    const int* __restrict__ cntA, const int* __restrict__ cntB,
    int* __restrict__ roA, int* __restrict__ roB,
    int* __restrict__ curA, int* __restrict__ curB,
    const int* __restrict__ partial, int N) {
    const int dir = blockIdx.y;
    const int* cnt = dir ? cntB : cntA;
    int* ro = dir ? roB : roA;
    int* cur = dir ? curB : curA;
    const int poff = partial[dir * 64 + blockIdx.x];
    const int i = blockIdx.x * SCAN_T + threadIdx.x;
    if (i < N) {
        int c = cnt[i];
        int r = ro[i + 1] + poff;
        ro[i + 1] = r;
        cur[i] = r - c;
        if (i == 0) ro[0] = 0;
    }
}

__global__ void fill_kernel(const int* __restrict__ eiA, const int* __restrict__ eiB,
                            const float* __restrict__ wA, const float* __restrict__ wB,
                            int E, int* curA, int* curB,
                            int* __restrict__ ssA, int* __restrict__ ssB,
                            float* __restrict__ swA, float* __restrict__ swB) {
    int i = blockIdx.x * blockDim.x + threadIdx.x;
    if (i < E) {
        int s = eiA[i], d = eiA[E + i];
        int pos = atomicAdd(&curA[d], 1);
        ssA[pos] = s; swA[pos] = wA[i];
    } else if (i < 2 * E) {
        int j = i - E;
        int s = eiB[j], d = eiB[E + j];
        int pos = atomicAdd(&curB[d], 1);
        ssB[pos] = s; swB[pos] = wB[j];
    }
}

// ---------------- GEMM [N,K]x[K,100] + fused att[n,h] = sum_c H[n,h*ch+c]*a[h*ch+c] ----------------
struct GemmArgs {
    const float* X;
    const float* W;
    const float* a;
    float* H;
    float* att;
};

template <int K, int HEADS>
__global__ __launch_bounds__(128) void gemm_att_kernel(
    GemmArgs g0, GemmArgs g1, GemmArgs g2, GemmArgs g3, int N) {
    const GemmArgs ga[4] = {g0, g1, g2, g3};
    const GemmArgs g = ga[blockIdx.y];
    constexpr int NB = 16;
    constexpr int KT = (K % 20 == 0) ? 20 : 16;
    static_assert(K % KT == 0, "K tiling");
    __shared__ float4 Xs[NB][K / 4];
    __shared__ float att_s[NB * HEADS];
    const int tid = threadIdx.x;
    const int node0 = blockIdx.x * NB;  // N is a multiple of 16 (50000)
    const float4* Xg = (const float4*)(g.X + (size_t)node0 * K);
    for (int i = tid; i < NB * (K / 4); i += 128) ((float4*)Xs)[i] = Xg[i];
    if (tid < NB * HEADS) att_s[tid] = 0.f;
    __syncthreads();
    const int c = tid;
    float acc[NB];
#pragma unroll
    for (int i = 0; i < NB; ++i) acc[i] = 0.f;
    if (c < 100) {
        for (int kt = 0; kt < K; kt += KT) {
            float wr[KT];
#pragma unroll
            for (int j = 0; j < KT; ++j) wr[j] = g.W[(kt + j) * 100 + c];
#pragma unroll
            for (int i = 0; i < NB; ++i) {
#pragma unroll
                for (int q = 0; q < KT / 4; ++q) {
                    float4 xv = Xs[i][kt / 4 + q];
                    acc[i] = fmaf(xv.x, wr[4 * q + 0], acc[i]);
                    acc[i] = fmaf(xv.y, wr[4 * q + 1], acc[i]);
                    acc[i] = fmaf(xv.z, wr[4 * q + 2], acc[i]);
                    acc[i] = fmaf(xv.w, wr[4 * q + 3], acc[i]);
                }
            }
        }
        const float av = g.a[c];
        const int h = c / (100 / HEADS);
#pragma unroll
        for (int i = 0; i < NB; ++i) {
            g.H[(size_t)(node0 + i) * 100 + c] = acc[i];
            atomicAdd(&att_s[i * HEADS + h], acc[i] * av);
        }
    }
    __syncthreads();
    if (tid < NB * HEADS) g.att[(size_t)node0 * HEADS + tid] = att_s[tid];
}

// ---------------- layer-1 gather: wave per dst node, heads=4, ch=25, edge weight, elu ----------------
struct Gather4Args {
    const int* ro;
    const int* ss;
    const float* sw;
    const float* hs;   // [Ns,100]
    const float* as_;  // [Ns,4]
    const float* ad;   // [Nd,4]
    const float* ce;   // [4]
    const float* bias; // [100]
    float* outp;       // [Nd,100]
};

__global__ __launch_bounds__(256) void gather4_kernel(Gather4Args ga0, Gather4Args ga1, int Nd) {
    const Gather4Args ga[2] = {ga0, ga1};
    const Gather4Args g = ga[blockIdx.y];
    int wid = (int)((blockIdx.x * blockDim.x + threadIdx.x) >> 6);
    if (wid >= Nd) return;
    const int n = __builtin_amdgcn_readfirstlane(wid);
    const int lane = threadIdx.x & 63;
    const int beg = g.ro[n], end = g.ro[n + 1];
    const int c0 = lane, c1 = 64 + lane;
    const bool has1 = (c1 < 100);
    const int h0 = c0 / 25;
    const int h1 = (c1 / 25) & 3;  // valid head when has1; masked to stay in-bounds otherwise
    const float ce0 = g.ce[h0], ce1 = g.ce[h1];
    const float ad0 = g.ad[n * 4 + h0], ad1 = g.ad[n * 4 + h1];
    float acc0 = 0.f, acc1 = 0.f, d0 = 0.f, d1 = 0.f;
    int p = beg;
    for (; p + 1 < end; p += 2) {
        const int sa = g.ss[p], sb = g.ss[p + 1];
        const float wa = g.sw[p], wb = g.sw[p + 1];
        const float* ara = g.as_ + (size_t)sa * 4;
        const float* arb = g.as_ + (size_t)sb * 4;
        const float* hra = g.hs + (size_t)sa * 100;
        const float* hrb = g.hs + (size_t)sb * 100;
        float la0 = ara[h0] + ad0 + wa * ce0;
        float la1 = ara[h1] + ad1 + wa * ce1;
        float lb0 = arb[h0] + ad0 + wb * ce0;
        float lb1 = arb[h1] + ad1 + wb * ce1;
        la0 = fmaxf(la0, 0.2f * la0); la1 = fmaxf(la1, 0.2f * la1);
        lb0 = fmaxf(lb0, 0.2f * lb0); lb1 = fmaxf(lb1, 0.2f * lb1);
        const float pa0 = __expf(la0), pa1 = __expf(la1);
        const float pb0 = __expf(lb0), pb1 = __expf(lb1);
        const float va0 = hra[c0], vb0 = hrb[c0];
        const float va1 = has1 ? hra[c1] : 0.f;
        const float vb1 = has1 ? hrb[c1] : 0.f;
        acc0 = fmaf(pa0, va0, acc0); acc0 = fmaf(pb0, vb0, acc0);
        acc1 = fmaf(pa1, va1, acc1); acc1 = fmaf(pb1, vb1, acc1);
        d0 += pa0 + pb0;
        d1 += pa1 + pb1;
    }
    if (p < end) {
        const int s = g.ss[p];
        const float w = g.sw[p];
        const float* asrow = g.as_ + (size_t)s * 4;
        float l0 = asrow[h0] + ad0 + w * ce0;
        float l1 = asrow[h1] + ad1 + w * ce1;
        l0 = fmaxf(l0, 0.2f * l0);
        l1 = fmaxf(l1, 0.2f * l1);
        const float p0 = __expf(l0);
        const float p1 = __expf(l1);
        const float* hrow = g.hs + (size_t)s * 100;
        acc0 = fmaf(p0, hrow[c0], acc0);
        acc1 = fmaf(p1, has1 ? hrow[c1] : 0.f, acc1);
        d0 += p0;
        d1 += p1;
    }
    float r0 = (end > beg) ? acc0 / d0 : 0.f;
    float r1 = (end > beg) ? acc1 / d1 : 0.f;
    r0 += g.bias[c0];
    r0 = (r0 > 0.f) ? r0 : (__expf(r0) - 1.f);  // elu
    g.outp[(size_t)n * 100 + c0] = r0;
    if (has1) {
        r1 += g.bias[c1];
        r1 = (r1 > 0.f) ? r1 : (__expf(r1) - 1.f);
        g.outp[(size_t)n * 100 + c1] = r1;
    }
}

// ---------------- layer-2 gather: wave per dst node, heads=1, ch=100, no edge feat, no elu ----------------
struct Gather1Args {
    const int* ro;
    const int* ss;
    const float* hs;   // [Ns,100]
    const float* as_;  // [Ns]
    const float* ad;   // [Nd]
    const float* bias; // [100]
    float* outp;       // [Nd,100]
};

__global__ __launch_bounds__(256) void gather1_kernel(Gather1Args ga0, Gather1Args ga1, int Nd) {
    const Gather1Args ga[2] = {ga0, ga1};
    const Gather1Args g = ga[blockIdx.y];
    int wid = (int)((blockIdx.x * blockDim.x + threadIdx.x) >> 6);
    if (wid >= Nd) return;
    const int n = __builtin_amdgcn_readfirstlane(wid);
    const int lane = threadIdx.x & 63;
    const int beg = g.ro[n], end = g.ro[n + 1];
    const int c0 = lane, c1 = 64 + lane;
    const bool has1 = (c1 < 100);
    const float adn = g.ad[n];
    float acc0 = 0.f, acc1 = 0.f, d0 = 0.f;
    int p = beg;
    for (; p + 1 < end; p += 2) {
        const int sa = g.ss[p], sb = g.ss[p + 1];
        float la = g.as_[sa] + adn;
        float lb = g.as_[sb] + adn;
        la = fmaxf(la, 0.2f * la);
        lb = fmaxf(lb, 0.2f * lb);
        const float pa = __expf(la), pb = __expf(lb);
        const float* hra = g.hs + (size_t)sa * 100;
        const float* hrb = g.hs + (size_t)sb * 100;
        const float va0 = hra[c0], vb0 = hrb[c0];
        const float va1 = has1 ? hra[c1] : 0.f;
        const float vb1 = has1 ? hrb[c1] : 0.f;
        acc0 = fmaf(pa, va0, acc0); acc0 = fmaf(pb, vb0, acc0);
        acc1 = fmaf(pa, va1, acc1); acc1 = fmaf(pb, vb1, acc1);
        d0 += pa + pb;
    }
    if (p < end) {
        const int s = g.ss[p];
        float l = g.as_[s] + adn;
        l = fmaxf(l, 0.2f * l);
        const float pe = __expf(l);
        const float* hrow = g.hs + (size_t)s * 100;
        acc0 = fmaf(pe, hrow[c0], acc0);
        acc1 = fmaf(pe, has1 ? hrow[c1] : 0.f, acc1);
        d0 += pe;
    }
    float r0 = (end > beg) ? acc0 / d0 : 0.f;
    float r1 = (end > beg) ? acc1 / d0 : 0.f;
    g.outp[(size_t)n * 100 + c0] = r0 + g.bias[c0];
    if (has1) g.outp[(size_t)n * 100 + c1] = r1 + g.bias[c1];
}

extern "C" void kernel_launch(void* const* d_in, const int* in_sizes, int n_in,
                              void* d_out, int out_size, void* d_ws, size_t ws_size,
                              hipStream_t stream) {
    const float* x_A   = (const float*)d_in[0];
    const float* x_B   = (const float*)d_in[1];
    const int*   ei_AB = (const int*)d_in[2];
    const int*   ei_BA = (const int*)d_in[3];
    const float* w_AB  = (const float*)d_in[4];
    const float* w_BA  = (const float*)d_in[5];
    const float* l1AB_Ws = (const float*)d_in[6];
    const float* l1AB_Wd = (const float*)d_in[7];
    const float* l1AB_as = (const float*)d_in[8];
    const float* l1AB_ad = (const float*)d_in[9];
    const float* l1AB_We = (const float*)d_in[10];
    const float* l1AB_ae = (const float*)d_in[11];
    const float* l1AB_b  = (const float*)d_in[12];
    const float* l2AB_Ws = (const float*)d_in[13];
    const float* l2AB_Wd = (const float*)d_in[14];
    const float* l2AB_as = (const float*)d_in[15];
    const float* l2AB_ad = (const float*)d_in[16];
    const float* l2AB_b  = (const float*)d_in[17];
    const float* l1BA_Ws = (const float*)d_in[18];
    const float* l1BA_Wd = (const float*)d_in[19];
    const float* l1BA_as = (const float*)d_in[20];
    const float* l1BA_ad = (const float*)d_in[21];
    const float* l1BA_We = (const float*)d_in[22];
    const float* l1BA_ae = (const float*)d_in[23];
    const float* l1BA_b  = (const float*)d_in[24];
    const float* l2BA_Ws = (const float*)d_in[25];
    const float* l2BA_Wd = (const float*)d_in[26];
    const float* l2BA_as = (const float*)d_in[27];
    const float* l2BA_ad = (const float*)d_in[28];
    const float* l2BA_b  = (const float*)d_in[29];

    const int N = NNODES, E = NEDGES;

    // ---- workspace carve (4-byte elements, 64-element aligned) ----
    size_t o = 0;
    auto alloc = [&](size_t n) { size_t r = o; o += (n + 63) & ~(size_t)63; return r; };
    size_t cntA = alloc(N), cntB = alloc(N);
    size_t roA = alloc(N + 1), roB = alloc(N + 1);
    size_t curA = alloc(N), curB = alloc(N);
    size_t ssA = alloc(E), ssB = alloc(E);
    size_t swA = alloc(E), swB = alloc(E);
    size_t ce8 = alloc(8);
    size_t part = alloc(128);
    size_t h1sA = alloc((size_t)N * 100), h1dB = alloc((size_t)N * 100);
    size_t h1sB = alloc((size_t)N * 100), h1dA = alloc((size_t)N * 100);
    size_t a1sA = alloc((size_t)N * 4), a1dB = alloc((size_t)N * 4);
    size_t a1sB = alloc((size_t)N * 4), a1dA = alloc((size_t)N * 4);
    size_t hA1 = alloc((size_t)N * 100), hB1 = alloc((size_t)N * 100);
    (void)ws_size;

    float* wsf = (float*)d_ws;
    int*   wsi = (int*)d_ws;

    // zero edge-count histograms (cntA..cntB contiguous span)
    hipMemsetAsync(wsi + cntA, 0, sizeof(int) * (cntB + N - cntA), stream);

    ce_kernel<<<2, 128, 0, stream>>>(l1AB_We, l1AB_ae, l1BA_We, l1BA_ae, wsf + ce8);

    const int eb = (2 * E + 255) / 256;
    count_kernel<<<eb, 256, 0, stream>>>(ei_AB, ei_BA, E, wsi + cntA, wsi + cntB);
    scanA_kernel<<<dim3(SCAN_NBLK, 2), SCAN_T, 0, stream>>>(
        wsi + cntA, wsi + cntB, wsi + roA, wsi + roB, wsi + part, N);
    scanB_kernel<<<1, 128, 0, stream>>>(wsi + part, SCAN_NBLK);
    scanC_kernel<<<dim3(SCAN_NBLK, 2), SCAN_T, 0, stream>>>(
        wsi + cntA, wsi + cntB, wsi + roA, wsi + roB, wsi + curA, wsi + curB, wsi + part, N);
    fill_kernel<<<eb, 256, 0, stream>>>(ei_AB, ei_BA, w_AB, w_BA, E, wsi + curA, wsi + curB,
                                        wsi + ssA, wsi + ssB, wsf + swA, wsf + swB);

    const int gb = N / 16;  // 3125
    // layer-1 node transforms (4 independent gemms, one launch)
    {
        GemmArgs g0 = {x_A, l1AB_Ws, l1AB_as, wsf + h1sA, wsf + a1sA};
        GemmArgs g1 = {x_B, l1AB_Wd, l1AB_ad, wsf + h1dB, wsf + a1dB};
        GemmArgs g2 = {x_B, l1BA_Ws, l1BA_as, wsf + h1sB, wsf + a1sB};
        GemmArgs g3 = {x_A, l1BA_Wd, l1BA_ad, wsf + h1dA, wsf + a1dA};
        gemm_att_kernel<128, 4><<<dim3(gb, 4), 128, 0, stream>>>(g0, g1, g2, g3, N);
    }

    const int wb = (N + 3) / 4;  // wave per node, 4 waves/block
    {
        Gather4Args g0 = {wsi + roA, wsi + ssA, wsf + swA, wsf + h1sA, wsf + a1sA,
                          wsf + a1dB, wsf + ce8, l1AB_b, wsf + hB1};
        Gather4Args g1 = {wsi + roB, wsi + ssB, wsf + swB, wsf + h1sB, wsf + a1sB,
                          wsf + a1dA, wsf + ce8 + 4, l1BA_b, wsf + hA1};
        gather4_kernel<<<dim3(wb, 2), 256, 0, stream>>>(g0, g1, N);
    }

    // layer-2 node transforms (reuse layer-1 buffers)
    {
        GemmArgs g0 = {wsf + hA1, l2AB_Ws, l2AB_as, wsf + h1sA, wsf + a1sA};
        GemmArgs g1 = {wsf + hB1, l2AB_Wd, l2AB_ad, wsf + h1dB, wsf + a1dB};
        GemmArgs g2 = {wsf + hB1, l2BA_Ws, l2BA_as, wsf + h1sB, wsf + a1sB};
        GemmArgs g3 = {wsf + hA1, l2BA_Wd, l2BA_ad, wsf + h1dA, wsf + a1dA};
        gemm_att_kernel<100, 1><<<dim3(gb, 4), 128, 0, stream>>>(g0, g1, g2, g3, N);
    }

    float* out = (float*)d_out;
    // oA = BA direction (dst in A) -> d_out[0..5M); oB = AB direction -> d_out[5M..10M)
    {
        Gather1Args g0 = {wsi + roA, wsi + ssA, wsf + h1sA, wsf + a1sA, wsf + a1dB,
                          l2AB_b, out + (size_t)N * 100};
        Gather1Args g1 = {wsi + roB, wsi + ssB, wsf + h1sB, wsf + a1sB, wsf + a1dA,
                          l2BA_b, out};
        gather1_kernel<<<dim3(wb, 2), 256, 0, stream>>>(g0, g1, N);
    }
}

// Round 3
// 1538.342 us; speedup vs baseline: 1.0113x; 1.0113x over previous
//
#include <hip/hip_runtime.h>

// HeteroGAT: 2-layer bipartite GAT (heads=4,ch=25 concat + edge feat; then heads=1,ch=100).
// R3: gemm rewritten lane=node (64 nodes/wave, 4 waves x 25 cols), X in LDS stride K+1
//     (conflict-free per-k ds_read_b32), W via wave-uniform s_load double-buffer,
//     H stored coalesced via LDS transpose. Old gemm was 385us @ 35% VALU, LDS-pipe bound.

#define NNODES 50000
#define NEDGES 800000
#define SCAN_T 1024
#define SCAN_NBLK ((NNODES + SCAN_T - 1) / SCAN_T)  // 49

// ---------------- ce[h] = sum_c We[h*25+c]*ae[h*25+c] (edge-attn constant) ----------------
__global__ void ce_kernel(const float* __restrict__ WeA, const float* __restrict__ aeA,
                          const float* __restrict__ WeB, const float* __restrict__ aeB,
                          float* __restrict__ ce /*[8]: 0..3=AB, 4..7=BA*/) {
    const float* We = blockIdx.x ? WeB : WeA;
    const float* ae = blockIdx.x ? aeB : aeA;
    __shared__ float s[4];
    int tid = threadIdx.x;
    if (tid < 4) s[tid] = 0.f;
    __syncthreads();
    if (tid < 100) atomicAdd(&s[tid / 25], We[tid] * ae[tid]);
    __syncthreads();
    if (tid < 4) ce[blockIdx.x * 4 + tid] = s[tid];
}

// ---------------- CSR build ----------------
__global__ void count_kernel(const int* __restrict__ eiA, const int* __restrict__ eiB,
                             int E, int* cntA, int* cntB) {
    int i = blockIdx.x * blockDim.x + threadIdx.x;
    if (i < E) atomicAdd(&cntA[eiA[E + i]], 1);
    else if (i < 2 * E) atomicAdd(&cntB[eiB[E + (i - E)]], 1);
}

// inclusive block-scan of cnt into ro[i+1] (no cross-block offset yet) + block totals
__global__ __launch_bounds__(SCAN_T) void scanA_kernel(
    const int* __restrict__ cntA, const int* __restrict__ cntB,
    int* __restrict__ roA, int* __restrict__ roB, int* __restrict__ partial, int N) {
    const int dir = blockIdx.y;
    const int* cnt = dir ? cntB : cntA;
    int* ro = dir ? roB : roA;
    const int tid = threadIdx.x;
    const int i = blockIdx.x * SCAN_T + tid;
    __shared__ int sm[SCAN_T];
    sm[tid] = (i < N) ? cnt[i] : 0;
    __syncthreads();
    for (int off = 1; off < SCAN_T; off <<= 1) {
        int t = (tid >= off) ? sm[tid - off] : 0;
        __syncthreads();
        sm[tid] += t;
        __syncthreads();
    }
    if (i < N) ro[i + 1] = sm[tid];
    if (tid == SCAN_T - 1) partial[dir * 64 + blockIdx.x] = sm[tid];
}

// exclusive scan of per-block totals (49 per direction) — tiny, one block
__global__ void scanB_kernel(int* __restrict__ partial, int nblk) {
    __shared__ int sm[128];
    const int tid = threadIdx.x;
    sm[tid] = ((tid & 63) < nblk) ? partial[tid] : 0;
    __syncthreads();
    if (tid < 2) {
        int run = 0;
        for (int b = 0; b < nblk; ++b) {
            int t = sm[tid * 64 + b];
            sm[tid * 64 + b] = run;
            run += t;
        }
    }
    __syncthreads();
    partial[tid] = sm[tid];
}

// add block offsets; derive cur[i] = row start
__global__ __launch_bounds__(SCAN_T) void scanC_kernel(
    const int* __restrict__ cntA, const int* __restrict__ cntB,
    int* __restrict__ roA, int* __restrict__ roB,
    int* __restrict__ curA, int* __restrict__ curB,
    const int* __restrict__ partial, int N) {
    const int dir = blockIdx.y;
    const int* cnt = dir ? cntB : cntA;
    int* ro = dir ? roB : roA;
    int* cur = dir ? curB : curA;
    const int poff = partial[dir * 64 + blockIdx.x];
    const int i = blockIdx.x * SCAN_T + threadIdx.x;
    if (i < N) {
        int c = cnt[i];
        int r = ro[i + 1] + poff;
        ro[i + 1] = r;
        cur[i] = r - c;
        if (i == 0) ro[0] = 0;
    }
}

__global__ void fill_kernel(const int* __restrict__ eiA, const int* __restrict__ eiB,
                            const float* __restrict__ wA, const float* __restrict__ wB,
                            int E, int* curA, int* curB,
                            int* __restrict__ ssA, int* __restrict__ ssB,
                            float* __restrict__ swA, float* __restrict__ swB) {
    int i = blockIdx.x * blockDim.x + threadIdx.x;
    if (i < E) {
        int s = eiA[i], d = eiA[E + i];
        int pos = atomicAdd(&curA[d], 1);
        ssA[pos] = s; swA[pos] = wA[i];
    } else if (i < 2 * E) {
        int j = i - E;
        int s = eiB[j], d = eiB[E + j];
        int pos = atomicAdd(&curB[d], 1);
        ssB[pos] = s; swB[pos] = wB[j];
    }
}

// ---------------- GEMM [N,K]x[K,100] + fused att[n,h] = sum_c H[n,h*ch+c]*a[h*ch+c] ----------------
// lane = node (64 nodes/block), wave w handles cols [25w, 25w+25).
// X in LDS [node][k] stride S=K+1 (odd -> 2 lanes/bank, conflict-free).
// W loaded wave-uniform (readfirstlane'd col base -> s_load), double-buffered over k.
// H written via LDS transpose for fully coalesced stores.
struct GemmArgs {
    const float* X;
    const float* W;
    const float* a;
    float* H;
    float* att;
};

template <int K, int HEADS>
__global__ __launch_bounds__(256) void gemm_att_kernel(
    GemmArgs g0, GemmArgs g1, GemmArgs g2, GemmArgs g3, int N) {
    const GemmArgs ga[4] = {g0, g1, g2, g3};
    const GemmArgs g = ga[blockIdx.y];
    constexpr int S = K + 1;
    __shared__ float Xs[64 * S];
    __shared__ float attp[4][64];
    const int tid = threadIdx.x;
    const int lane = tid & 63;
    const int w = tid >> 6;
    const int node0 = blockIdx.x * 64;
    const int nvalid = (N - node0 < 64) ? (N - node0) : 64;

    // stage X (coalesced global reads, scalar LDS writes into padded layout)
    for (int idx = tid; idx < 64 * K; idx += 256) {
        int node = idx / K;
        int k = idx - node * K;
        float v = (node < nvalid) ? g.X[(size_t)(node0 + node) * K + k] : 0.f;
        Xs[node * S + k] = v;
    }
    __syncthreads();

    const int c0 = __builtin_amdgcn_readfirstlane(25 * w);  // force SGPR -> s_load for W
    const float* Wp = g.W + c0;
    const float* xrow = Xs + lane * S;

    float acc[25];
#pragma unroll
    for (int j = 0; j < 25; ++j) acc[j] = 0.f;

    float wb0[25], wb1[25];
#pragma unroll
    for (int j = 0; j < 25; ++j) wb0[j] = Wp[j];  // k=0

    for (int k = 0; k < K; k += 2) {
        // body A: use wb0 (k), prefetch wb1 (k+1)
#pragma unroll
        for (int j = 0; j < 25; ++j) wb1[j] = Wp[(k + 1) * 100 + j];
        const float xa = xrow[k];
#pragma unroll
        for (int j = 0; j < 25; ++j) acc[j] = fmaf(xa, wb0[j], acc[j]);
        // body B: use wb1 (k+1), prefetch wb0 (k+2)
        if (k + 2 < K) {
#pragma unroll
            for (int j = 0; j < 25; ++j) wb0[j] = Wp[(k + 2) * 100 + j];
        }
        const float xb = xrow[k + 1];
#pragma unroll
        for (int j = 0; j < 25; ++j) acc[j] = fmaf(xb, wb1[j], acc[j]);
    }

    // attention partial for this (node, col-range): uniform 'a' reads -> s_load
    float ap = 0.f;
#pragma unroll
    for (int j = 0; j < 25; ++j) ap = fmaf(acc[j], g.a[c0 + j], ap);

    __syncthreads();  // all waves done reading Xs; safe to reuse as H transpose buffer
#pragma unroll
    for (int j = 0; j < 25; ++j) Xs[lane * S + c0 + j] = acc[j];
    attp[w][lane] = ap;
    __syncthreads();

    // coalesced H store: 6400 floats contiguous from H[node0*100]
    for (int i = 0; i < 25; ++i) {
        int idx = tid + i * 256;
        int node = idx / 100;
        int c = idx - node * 100;
        if (node < nvalid) g.H[(size_t)node0 * 100 + idx] = Xs[node * S + c];
    }
    // att store
    if (HEADS == 4) {
        // head h == wave w (25 cols per head); att[n*4+h]
        int node = tid >> 2, h = tid & 3;
        if (node < nvalid) g.att[(size_t)(node0 + node) * 4 + h] = attp[h][node];
    } else {
        if (tid < 64 && tid < nvalid)
            g.att[node0 + tid] = attp[0][tid] + attp[1][tid] + attp[2][tid] + attp[3][tid];
    }
}

// ---------------- layer-1 gather: wave per dst node, heads=4, ch=25, edge weight, elu ----------------
struct Gather4Args {
    const int* ro;
    const int* ss;
    const float* sw;
    const float* hs;   // [Ns,100]
    const float* as_;  // [Ns,4]
    const float* ad;   // [Nd,4]
    const float* ce;   // [4]
    const float* bias; // [100]
    float* outp;       // [Nd,100]
};

__global__ __launch_bounds__(256) void gather4_kernel(Gather4Args ga0, Gather4Args ga1, int Nd) {
    const Gather4Args ga[2] = {ga0, ga1};
    const Gather4Args g = ga[blockIdx.y];
    int wid = (int)((blockIdx.x * blockDim.x + threadIdx.x) >> 6);
    if (wid >= Nd) return;
    const int n = __builtin_amdgcn_readfirstlane(wid);
    const int lane = threadIdx.x & 63;
    const int beg = g.ro[n], end = g.ro[n + 1];
    const int c0 = lane, c1 = 64 + lane;
    const bool has1 = (c1 < 100);
    const int h0 = c0 / 25;
    const int h1 = (c1 / 25) & 3;  // valid head when has1; masked to stay in-bounds otherwise
    const float ce0 = g.ce[h0], ce1 = g.ce[h1];
    const float ad0 = g.ad[n * 4 + h0], ad1 = g.ad[n * 4 + h1];
    float acc0 = 0.f, acc1 = 0.f, d0 = 0.f, d1 = 0.f;
    int p = beg;
    for (; p + 1 < end; p += 2) {
        const int sa = g.ss[p], sb = g.ss[p + 1];
        const float wa = g.sw[p], wb = g.sw[p + 1];
        const float* ara = g.as_ + (size_t)sa * 4;
        const float* arb = g.as_ + (size_t)sb * 4;
        const float* hra = g.hs + (size_t)sa * 100;
        const float* hrb = g.hs + (size_t)sb * 100;
        float la0 = ara[h0] + ad0 + wa * ce0;
        float la1 = ara[h1] + ad1 + wa * ce1;
        float lb0 = arb[h0] + ad0 + wb * ce0;
        float lb1 = arb[h1] + ad1 + wb * ce1;
        la0 = fmaxf(la0, 0.2f * la0); la1 = fmaxf(la1, 0.2f * la1);
        lb0 = fmaxf(lb0, 0.2f * lb0); lb1 = fmaxf(lb1, 0.2f * lb1);
        const float pa0 = __expf(la0), pa1 = __expf(la1);
        const float pb0 = __expf(lb0), pb1 = __expf(lb1);
        const float va0 = hra[c0], vb0 = hrb[c0];
        const float va1 = has1 ? hra[c1] : 0.f;
        const float vb1 = has1 ? hrb[c1] : 0.f;
        acc0 = fmaf(pa0, va0, acc0); acc0 = fmaf(pb0, vb0, acc0);
        acc1 = fmaf(pa1, va1, acc1); acc1 = fmaf(pb1, vb1, acc1);
        d0 += pa0 + pb0;
        d1 += pa1 + pb1;
    }
    if (p < end) {
        const int s = g.ss[p];
        const float w = g.sw[p];
        const float* asrow = g.as_ + (size_t)s * 4;
        float l0 = asrow[h0] + ad0 + w * ce0;
        float l1 = asrow[h1] + ad1 + w * ce1;
        l0 = fmaxf(l0, 0.2f * l0);
        l1 = fmaxf(l1, 0.2f * l1);
        const float p0 = __expf(l0);
        const float p1 = __expf(l1);
        const float* hrow = g.hs + (size_t)s * 100;
        acc0 = fmaf(p0, hrow[c0], acc0);
        acc1 = fmaf(p1, has1 ? hrow[c1] : 0.f, acc1);
        d0 += p0;
        d1 += p1;
    }
    float r0 = (end > beg) ? acc0 / d0 : 0.f;
    float r1 = (end > beg) ? acc1 / d1 : 0.f;
    r0 += g.bias[c0];
    r0 = (r0 > 0.f) ? r0 : (__expf(r0) - 1.f);  // elu
    g.outp[(size_t)n * 100 + c0] = r0;
    if (has1) {
        r1 += g.bias[c1];
        r1 = (r1 > 0.f) ? r1 : (__expf(r1) - 1.f);
        g.outp[(size_t)n * 100 + c1] = r1;
    }
}

// ---------------- layer-2 gather: wave per dst node, heads=1, ch=100, no edge feat, no elu ----------------
struct Gather1Args {
    const int* ro;
    const int* ss;
    const float* hs;   // [Ns,100]
    const float* as_;  // [Ns]
    const float* ad;   // [Nd]
    const float* bias; // [100]
    float* outp;       // [Nd,100]
};

__global__ __launch_bounds__(256) void gather1_kernel(Gather1Args ga0, Gather1Args ga1, int Nd) {
    const Gather1Args ga[2] = {ga0, ga1};
    const Gather1Args g = ga[blockIdx.y];
    int wid = (int)((blockIdx.x * blockDim.x + threadIdx.x) >> 6);
    if (wid >= Nd) return;
    const int n = __builtin_amdgcn_readfirstlane(wid);
    const int lane = threadIdx.x & 63;
    const int beg = g.ro[n], end = g.ro[n + 1];
    const int c0 = lane, c1 = 64 + lane;
    const bool has1 = (c1 < 100);
    const float adn = g.ad[n];
    float acc0 = 0.f, acc1 = 0.f, d0 = 0.f;
    int p = beg;
    for (; p + 1 < end; p += 2) {
        const int sa = g.ss[p], sb = g.ss[p + 1];
        float la = g.as_[sa] + adn;
        float lb = g.as_[sb] + adn;
        la = fmaxf(la, 0.2f * la);
        lb = fmaxf(lb, 0.2f * lb);
        const float pa = __expf(la), pb = __expf(lb);
        const float* hra = g.hs + (size_t)sa * 100;
        const float* hrb = g.hs + (size_t)sb * 100;
        const float va0 = hra[c0], vb0 = hrb[c0];
        const float va1 = has1 ? hra[c1] : 0.f;
        const float vb1 = has1 ? hrb[c1] : 0.f;
        acc0 = fmaf(pa, va0, acc0); acc0 = fmaf(pb, vb0, acc0);
        acc1 = fmaf(pa, va1, acc1); acc1 = fmaf(pb, vb1, acc1);
        d0 += pa + pb;
    }
    if (p < end) {
        const int s = g.ss[p];
        float l = g.as_[s] + adn;
        l = fmaxf(l, 0.2f * l);
        const float pe = __expf(l);
        const float* hrow = g.hs + (size_t)s * 100;
        acc0 = fmaf(pe, hrow[c0], acc0);
        acc1 = fmaf(pe, has1 ? hrow[c1] : 0.f, acc1);
        d0 += pe;
    }
    float r0 = (end > beg) ? acc0 / d0 : 0.f;
    float r1 = (end > beg) ? acc1 / d0 : 0.f;
    g.outp[(size_t)n * 100 + c0] = r0 + g.bias[c0];
    if (has1) g.outp[(size_t)n * 100 + c1] = r1 + g.bias[c1];
}

extern "C" void kernel_launch(void* const* d_in, const int* in_sizes, int n_in,
                              void* d_out, int out_size, void* d_ws, size_t ws_size,
                              hipStream_t stream) {
    const float* x_A   = (const float*)d_in[0];
    const float* x_B   = (const float*)d_in[1];
    const int*   ei_AB = (const int*)d_in[2];
    const int*   ei_BA = (const int*)d_in[3];
    const float* w_AB  = (const float*)d_in[4];
    const float* w_BA  = (const float*)d_in[5];
    const float* l1AB_Ws = (const float*)d_in[6];
    const float* l1AB_Wd = (const float*)d_in[7];
    const float* l1AB_as = (const float*)d_in[8];
    const float* l1AB_ad = (const float*)d_in[9];
    const float* l1AB_We = (const float*)d_in[10];
    const float* l1AB_ae = (const float*)d_in[11];
    const float* l1AB_b  = (const float*)d_in[12];
    const float* l2AB_Ws = (const float*)d_in[13];
    const float* l2AB_Wd = (const float*)d_in[14];
    const float* l2AB_as = (const float*)d_in[15];
    const float* l2AB_ad = (const float*)d_in[16];
    const float* l2AB_b  = (const float*)d_in[17];
    const float* l1BA_Ws = (const float*)d_in[18];
    const float* l1BA_Wd = (const float*)d_in[19];
    const float* l1BA_as = (const float*)d_in[20];
    const float* l1BA_ad = (const float*)d_in[21];
    const float* l1BA_We = (const float*)d_in[22];
    const float* l1BA_ae = (const float*)d_in[23];
    const float* l1BA_b  = (const float*)d_in[24];
    const float* l2BA_Ws = (const float*)d_in[25];
    const float* l2BA_Wd = (const float*)d_in[26];
    const float* l2BA_as = (const float*)d_in[27];
    const float* l2BA_ad = (const float*)d_in[28];
    const float* l2BA_b  = (const float*)d_in[29];

    const int N = NNODES, E = NEDGES;

    // ---- workspace carve (4-byte elements, 64-element aligned) ----
    size_t o = 0;
    auto alloc = [&](size_t n) { size_t r = o; o += (n + 63) & ~(size_t)63; return r; };
    size_t cntA = alloc(N), cntB = alloc(N);
    size_t roA = alloc(N + 1), roB = alloc(N + 1);
    size_t curA = alloc(N), curB = alloc(N);
    size_t ssA = alloc(E), ssB = alloc(E);
    size_t swA = alloc(E), swB = alloc(E);
    size_t ce8 = alloc(8);
    size_t part = alloc(128);
    size_t h1sA = alloc((size_t)N * 100), h1dB = alloc((size_t)N * 100);
    size_t h1sB = alloc((size_t)N * 100), h1dA = alloc((size_t)N * 100);
    size_t a1sA = alloc((size_t)N * 4), a1dB = alloc((size_t)N * 4);
    size_t a1sB = alloc((size_t)N * 4), a1dA = alloc((size_t)N * 4);
    size_t hA1 = alloc((size_t)N * 100), hB1 = alloc((size_t)N * 100);
    (void)ws_size;

    float* wsf = (float*)d_ws;
    int*   wsi = (int*)d_ws;

    // zero edge-count histograms (cntA..cntB contiguous span)
    hipMemsetAsync(wsi + cntA, 0, sizeof(int) * (cntB + N - cntA), stream);

    ce_kernel<<<2, 128, 0, stream>>>(l1AB_We, l1AB_ae, l1BA_We, l1BA_ae, wsf + ce8);

    const int eb = (2 * E + 255) / 256;
    count_kernel<<<eb, 256, 0, stream>>>(ei_AB, ei_BA, E, wsi + cntA, wsi + cntB);
    scanA_kernel<<<dim3(SCAN_NBLK, 2), SCAN_T, 0, stream>>>(
        wsi + cntA, wsi + cntB, wsi + roA, wsi + roB, wsi + part, N);
    scanB_kernel<<<1, 128, 0, stream>>>(wsi + part, SCAN_NBLK);
    scanC_kernel<<<dim3(SCAN_NBLK, 2), SCAN_T, 0, stream>>>(
        wsi + cntA, wsi + cntB, wsi + roA, wsi + roB, wsi + curA, wsi + curB, wsi + part, N);
    fill_kernel<<<eb, 256, 0, stream>>>(ei_AB, ei_BA, w_AB, w_BA, E, wsi + curA, wsi + curB,
                                        wsi + ssA, wsi + ssB, wsf + swA, wsf + swB);

    const int gb = (N + 63) / 64;  // 782
    // layer-1 node transforms (4 independent gemms, one launch)
    {
        GemmArgs g0 = {x_A, l1AB_Ws, l1AB_as, wsf + h1sA, wsf + a1sA};
        GemmArgs g1 = {x_B, l1AB_Wd, l1AB_ad, wsf + h1dB, wsf + a1dB};
        GemmArgs g2 = {x_B, l1BA_Ws, l1BA_as, wsf + h1sB, wsf + a1sB};
        GemmArgs g3 = {x_A, l1BA_Wd, l1BA_ad, wsf + h1dA, wsf + a1dA};
        gemm_att_kernel<128, 4><<<dim3(gb, 4), 256, 0, stream>>>(g0, g1, g2, g3, N);
    }

    const int wb = (N + 3) / 4;  // wave per node, 4 waves/block
    {
        Gather4Args g0 = {wsi + roA, wsi + ssA, wsf + swA, wsf + h1sA, wsf + a1sA,
                          wsf + a1dB, wsf + ce8, l1AB_b, wsf + hB1};
        Gather4Args g1 = {wsi + roB, wsi + ssB, wsf + swB, wsf + h1sB, wsf + a1sB,
                          wsf + a1dA, wsf + ce8 + 4, l1BA_b, wsf + hA1};
        gather4_kernel<<<dim3(wb, 2), 256, 0, stream>>>(g0, g1, N);
    }

    // layer-2 node transforms (reuse layer-1 buffers)
    {
        GemmArgs g0 = {wsf + hA1, l2AB_Ws, l2AB_as, wsf + h1sA, wsf + a1sA};
        GemmArgs g1 = {wsf + hB1, l2AB_Wd, l2AB_ad, wsf + h1dB, wsf + a1dB};
        GemmArgs g2 = {wsf + hB1, l2BA_Ws, l2BA_as, wsf + h1sB, wsf + a1sB};
        GemmArgs g3 = {wsf + hA1, l2BA_Wd, l2BA_ad, wsf + h1dA, wsf + a1dA};
        gemm_att_kernel<100, 1><<<dim3(gb, 4), 256, 0, stream>>>(g0, g1, g2, g3, N);
    }

    float* out = (float*)d_out;
    // oA = BA direction (dst in A) -> d_out[0..5M); oB = AB direction -> d_out[5M..10M)
    {
        Gather1Args g0 = {wsi + roA, wsi + ssA, wsf + h1sA, wsf + a1sA, wsf + a1dB,
                          l2AB_b, out + (size_t)N * 100};
        Gather1Args g1 = {wsi + roB, wsi + ssB, wsf + h1sB, wsf + a1sB, wsf + a1dA,
                          l2BA_b, out};
        gather1_kernel<<<dim3(wb, 2), 256, 0, stream>>>(g0, g1, N);
    }
}